// Round 19
// baseline (74.275 us; speedup 1.0000x reference)
//
#include <hip/hip_runtime.h>
#include <hip/hip_bf16.h>
#include <hip/hip_fp16.h>

#define DD  256
#define HWD 1024
#define NN  32768
#define KK  1024
#define ZQ_SIZE (NN*DD)
#define IDX_OFF ZQ_SIZE
#define LOSS_OFF (ZQ_SIZE + NN)

// scratch layout (bytes) inside the z_q region of d_out (overwritten by gather)
#define CBH_OFF    0                      // fp16 codebook, 512 KB
#define CNORM_OFF  (KK*DD*2)              // 4 KB (biased +512)
#define ZSQ_OFF    (CNORM_OFF + KK*4)     // 512 floats (per-block zsq partials)
#define ROWREC_OFF (ZSQ_OFF + 2048)       // 4 floats/row packed top-3, 512 KB

#define DBIAS 512.0f
#define TH_REFINE 0.5f                     // >= 2*(fp16 err + pack err) + idx-bit slack
#define LOSS_SCALE (0.25f / (float)ZQ_SIZE)

typedef __attribute__((ext_vector_type(8))) _Float16 h16x8;
typedef __attribute__((ext_vector_type(4))) float f32x4;

__device__ __forceinline__ void gload16(const void* g, void* l) {
    __builtin_amdgcn_global_load_lds(
        (const __attribute__((address_space(1))) void*)g,
        (__attribute__((address_space(3))) void*)l, 16, 0, 0);
}
__device__ __forceinline__ unsigned short f16u(float x) {
    _Float16 h = (_Float16)x;
    return *reinterpret_cast<unsigned short*>(&h);
}
// bijective row swizzle: 2-way on both stride-1 reads and stride-4 writes
__device__ __forceinline__ int swz(int row) {
    return (row & 15) ^ ((row >> 2) & 15);
}

// ---------------------------------------------------------------------------
// A: codebook -> fp16 + fp32 row norms (biased by +DBIAS for packing)
__global__ __launch_bounds__(256)
void vq_prep_kernel(const float* __restrict__ cb, unsigned char* __restrict__ scratch) {
    _Float16* cbh = (_Float16*)(scratch + CBH_OFF);
    float* cn = (float*)(scratch + CNORM_OFF);
    int t = threadIdx.x;
    int row = blockIdx.x * 16 + (t >> 4);   // grid 64
    int dq  = t & 15;
    const float* rp = cb + (size_t)row * DD + dq * 16;
    float nrm = 0.f;
    __attribute__((aligned(16))) _Float16 h[16];
#pragma unroll
    for (int i = 0; i < 4; ++i) {
        float4 v = *(const float4*)(rp + i * 4);
        float xs[4] = {v.x, v.y, v.z, v.w};
#pragma unroll
        for (int j = 0; j < 4; ++j) {
            float x = xs[j];
            h[i * 4 + j] = (_Float16)x;
            nrm = fmaf(x, x, nrm);
        }
    }
    *(uint4*)&cbh[(size_t)row * DD + dq * 16]     = *(uint4*)&h[0];
    *(uint4*)&cbh[(size_t)row * DD + dq * 16 + 8] = *(uint4*)&h[8];
#pragma unroll
    for (int m = 1; m < 16; m <<= 1) nrm += __shfl_xor(nrm, m, 64);
    if (dq == 0) cn[row] = nrm + DBIAS;
}

// ---------------------------------------------------------------------------
// B: fp16 MFMA distance-argmin (R16 verbatim — best measured: ~47.5 us)
__global__ __launch_bounds__(256) __attribute__((amdgpu_waves_per_eu(2, 2)))
void vq_mfma_argmin_kernel(const float* __restrict__ z, unsigned char* __restrict__ scratch) {
    const unsigned char* cbh_b = scratch + CBH_OFF;
    const float* cn_g = (const float*)(scratch + CNORM_OFF);
    float* zsqp = (float*)(scratch + ZSQ_OFF);
    float* rowrec = (float*)(scratch + ROWREC_OFF);

    __shared__ __attribute__((aligned(16))) short bufs[4 * 8192];  // 64 KB
    __shared__ float cn_l[KK];                                     // 4 KB (biased)
    __shared__ float zred[4];

    const int t    = threadIdx.x;
    const int w    = t >> 6;
    const int lane = t & 63;
    const int ln15 = lane & 15;
    const int lh   = lane >> 4;
    const int g     = w >> 1;        // row-group 0..1 (32 rows each)
    const int khalf = w & 1;         // 16-code half of each 32-code tile

    const int n0  = blockIdx.x * 64;
    const int b   = n0 >> 10;
    const int hw0 = n0 & 1023;

    const int ksub  = lane >> 5;
    const int chunk = lane & 31;

    const int klr   = khalf * 16 + ln15;     // code row within 32-code tile
    const int rbase = klr * 256;             // shorts
    const int rxor  = swz(klr) << 3;         // swizzle (short units)

    *(float4*)&cn_l[t * 4] = *(const float4*)(cn_g + t * 4);

    // ---- phase 1: coalesced z -> LDS (fp16, transposed, swizzled; short2 writes)
    {
        short* zlds = bufs;
        const int zd = t >> 4;               // 0..15: d-block zd*16..+15
        const int zq = t & 15;               // rows zq*4..+3
        const float* zb = z + (size_t)b * DD * HWD + hw0 + zq * 4;
        float zsq = 0.f;
#pragma unroll
        for (int p = 0; p < 16; p += 2) {
            int d0 = zd * 16 + p;
            float4 va = *(const float4*)(zb + (size_t)(d0 + 0) * HWD);
            float4 vb = *(const float4*)(zb + (size_t)(d0 + 1) * HWD);
            zsq = fmaf(va.x, va.x, zsq); zsq = fmaf(va.y, va.y, zsq);
            zsq = fmaf(va.z, va.z, zsq); zsq = fmaf(va.w, va.w, zsq);
            zsq = fmaf(vb.x, vb.x, zsq); zsq = fmaf(vb.y, vb.y, zsq);
            zsq = fmaf(vb.z, vb.z, zsq); zsq = fmaf(vb.w, vb.w, zsq);
            float xa[4] = {va.x, va.y, va.z, va.w};
            float xb[4] = {vb.x, vb.y, vb.z, vb.w};
#pragma unroll
            for (int i = 0; i < 4; ++i) {
                int row = zq * 4 + i;
                int idx = row * 256 + (d0 ^ (swz(row) << 3));   // even, b32-aligned
                unsigned pk = (unsigned)f16u(xa[i]) | ((unsigned)f16u(xb[i]) << 16);
                *(unsigned*)&zlds[idx] = pk;
            }
        }
#pragma unroll
        for (int m = 1; m < 64; m <<= 1) zsq += __shfl_xor(zsq, m, 64);
        if (lane == 0) zred[w] = zsq;
    }
    __syncthreads();

    // ---- phase 2: A-frags from LDS
    h16x8 ah[2][8];
#pragma unroll
    for (int nf = 0; nf < 2; ++nf) {
#pragma unroll
        for (int ds = 0; ds < 8; ++ds) {
            int row = g * 32 + nf * 16 + ln15;
            int d0  = ds * 32 + lh * 8;
            ah[nf][ds] = *(const h16x8*)&bufs[row * 256 + (d0 ^ (swz(row) << 3))];
        }
    }
    if (t == 0) zsqp[blockIdx.x] = (zred[0] + zred[1]) + (zred[2] + zred[3]);
    __syncthreads();   // all frag reads done before staging overwrites bufs

    auto STAGE = [&](int tt) {
#pragma unroll
        for (int si = 0; si < 4; ++si) {
            int s  = w * 4 + si;
            int kl = s * 2 + ksub;
            const unsigned char* src = cbh_b
                + (size_t)(tt * 32 + kl) * 512 + ((chunk ^ swz(kl)) << 4);
            gload16(src, &bufs[(tt & 3) * 8192 + s * 512]);
        }
    };

    float v1[8], v2[8];
#pragma unroll
    for (int s = 0; s < 8; ++s) { v1[s] = 3e38f; v2[s] = 3e38f; }

    auto COMPUTE = [&](int kt) {
        const short* cbt = &bufs[(kt & 3) * 8192];
        const float cnv = cn_l[kt * 32 + klr];               // biased
        const unsigned kbits = (unsigned)(kt * 32 + klr);
        f32x4 c0 = {0.f,0.f,0.f,0.f}, c1 = c0, c2 = c0, c3 = c0;
#pragma unroll
        for (int ds = 0; ds < 8; ds += 2) {
            const int ib0 = rbase + (((ds + 0) * 32 + lh * 8) ^ rxor);
            const int ib1 = rbase + (((ds + 1) * 32 + lh * 8) ^ rxor);
            h16x8 b0 = *(const h16x8*)&cbt[ib0];
            h16x8 b1 = *(const h16x8*)&cbt[ib1];
            c0 = __builtin_amdgcn_mfma_f32_16x16x32_f16(ah[0][ds + 0], b0, c0, 0, 0, 0);
            c2 = __builtin_amdgcn_mfma_f32_16x16x32_f16(ah[1][ds + 0], b0, c2, 0, 0, 0);
            c1 = __builtin_amdgcn_mfma_f32_16x16x32_f16(ah[0][ds + 1], b1, c1, 0, 0, 0);
            c3 = __builtin_amdgcn_mfma_f32_16x16x32_f16(ah[1][ds + 1], b1, c3, 0, 0, 0);
        }
        f32x4 s0 = c0 + c1, s1 = c2 + c3;
#pragma unroll
        for (int s = 0; s < 8; ++s) {
            float a = (s < 4) ? s0[s] : s1[s - 4];
            float dist = fmaf(-2.f, a, cnv);                 // positive (biased)
            float pd = __uint_as_float((__float_as_uint(dist) & 0xFFFFFC00u) | kbits);
            v2[s] = fminf(fmaxf(pd, v1[s]), v2[s]);          // med3
            v1[s] = fminf(pd, v1[s]);
        }
    };

    STAGE(0); STAGE(1); STAGE(2);

    for (int kt = 0; kt < 29; ++kt) {
        asm volatile("s_waitcnt vmcnt(8)" ::: "memory");
        __builtin_amdgcn_sched_barrier(0);
        __builtin_amdgcn_s_barrier();
        __builtin_amdgcn_sched_barrier(0);
        STAGE(kt + 3);
        COMPUTE(kt);
    }
    asm volatile("s_waitcnt vmcnt(8)" ::: "memory");
    __builtin_amdgcn_sched_barrier(0);
    __builtin_amdgcn_s_barrier();
    __builtin_amdgcn_sched_barrier(0);
    COMPUTE(29);
    asm volatile("s_waitcnt vmcnt(4)" ::: "memory");
    __builtin_amdgcn_sched_barrier(0);
    __builtin_amdgcn_s_barrier();
    __builtin_amdgcn_sched_barrier(0);
    COMPUTE(30);
    asm volatile("s_waitcnt vmcnt(0)" ::: "memory");
    __builtin_amdgcn_sched_barrier(0);
    __builtin_amdgcn_s_barrier();
    __builtin_amdgcn_sched_barrier(0);
    COMPUTE(31);

    // ---- per-row top-3 merge on packed floats (alias bufs; stride-65 pad)
    __syncthreads();
    float* redv = (float*)bufs;              // [64 lists][stride 65]
#pragma unroll
    for (int s = 0; s < 8; ++s) {
        int nf = s >> 2, r = s & 3;
        int rowb = g * 32 + nf * 16 + lh * 4 + r;   // C layout: row = lh*4+reg
        redv[klr * 65 + rowb]        = v1[s];
        redv[(32 + klr) * 65 + rowb] = v2[s];
    }
    __syncthreads();

    const int p = t >> 6, row = t & 63;
    float w1 = 3e38f, w2 = 3e38f, w3 = 3e38f;
#pragma unroll
    for (int q = 0; q < 16; ++q) {
        float v = redv[(p * 16 + q) * 65 + row];
        w3 = fminf(fmaxf(v, w2), w3);
        w2 = fminf(fmaxf(v, w1), w2);
        w1 = fminf(v, w1);
    }
    __syncthreads();
    {   // partials: [4 p][64 rows][3]
        float* pv = (float*)bufs;
        int base = (p * 64 + row) * 3;
        pv[base + 0] = w1; pv[base + 1] = w2; pv[base + 2] = w3;
    }
    __syncthreads();
    if (t < 64) {
        const float* pv = (const float*)bufs;
        float u1 = 3e38f, u2 = 3e38f, u3 = 3e38f;
#pragma unroll
        for (int i = 0; i < 12; ++i) {
            float v = pv[((i / 3) * 64 + t) * 3 + (i % 3)];
            u3 = fminf(fmaxf(v, u2), u3);
            u2 = fminf(fmaxf(v, u1), u2);
            u1 = fminf(v, u1);
        }
        float4 rec; rec.x = u1; rec.y = u2; rec.z = u3; rec.w = 0.f;
        *(float4*)&rowrec[(size_t)(n0 + t) * 4] = rec;
    }
}

// ---------------------------------------------------------------------------
// R: flagged rows (packed gap <= TH) -> exact fp32 recheck of top-3;
// loss = sum chosen dist + zsq partials (block 0). (R16 verbatim — passed.)
__global__ __launch_bounds__(256)
void vq_refine_kernel(const float* __restrict__ z, const float* __restrict__ cb,
                      const unsigned char* __restrict__ scratch, float* __restrict__ idx_out,
                      float* __restrict__ lossp) {
    const float* rowrec = (const float*)(scratch + ROWREC_OFF);
    const float* cn_g = (const float*)(scratch + CNORM_OFF);   // biased
    const float* zsqp = (const float*)(scratch + ZSQ_OFF);
    int n = blockIdx.x * 256 + threadIdx.x;   // grid 128
    int lane = threadIdx.x & 63;

    float4 rr = *(const float4*)&rowrec[(size_t)n * 4];
    unsigned b1 = __float_as_uint(rr.x);
    bool flag = (rr.y - rr.x) <= TH_REFINE;
    float lp = 0.f;
    if (!flag) {
        idx_out[n] = (float)(b1 & 1023u);
        lp = __uint_as_float(b1 & 0xFFFFFC00u) - DBIAS;   // approx dist for loss
    }

    unsigned long long mask = __ballot(flag);
    while (mask) {
        int li = __ffsll(mask) - 1;
        mask &= mask - 1;
        int nn  = __shfl(n, li);
        int kk1 = (int)(__float_as_uint(__shfl(rr.x, li)) & 1023u);
        int kk2 = (int)(__float_as_uint(__shfl(rr.y, li)) & 1023u);
        int kk3 = (int)(__float_as_uint(__shfl(rr.z, li)) & 1023u);
        int bb = nn >> 10, hw = nn & 1023;
        const float* zp  = z  + (size_t)bb * DD * HWD + hw;
        const float* c1p = cb + (size_t)kk1 * DD;
        const float* c2p = cb + (size_t)kk2 * DD;
        const float* c3p = cb + (size_t)kk3 * DD;
        float s1 = 0.f, s2 = 0.f, s3 = 0.f;
#pragma unroll
        for (int j = 0; j < 4; ++j) {
            int d = lane + 64 * j;
            float zv = zp[(size_t)d * HWD];
            s1 = fmaf(zv, c1p[d], s1);
            s2 = fmaf(zv, c2p[d], s2);
            s3 = fmaf(zv, c3p[d], s3);
        }
#pragma unroll
        for (int m = 32; m >= 1; m >>= 1) {
            s1 += __shfl_xor(s1, m, 64);
            s2 += __shfl_xor(s2, m, 64);
            s3 += __shfl_xor(s3, m, 64);
        }
        float e1 = (cn_g[kk1] - DBIAS) - 2.f * s1;
        float e2 = (cn_g[kk2] - DBIAS) - 2.f * s2;
        float e3 = (cn_g[kk3] - DBIAS) - 2.f * s3;
        float dch = e1; int kch = kk1;
        if (e2 < dch || (e2 == dch && kk2 < kch)) { dch = e2; kch = kk2; }
        if (e3 < dch || (e3 == dch && kk3 < kch)) { dch = e3; kch = kk3; }
        if (lane == 0) { idx_out[nn] = (float)kch; lp += dch; }
    }

    // fold zsq partials (block 0; 512 floats, 2/thread)
    if (blockIdx.x == 0) {
        const float2 zv = *(const float2*)&zsqp[threadIdx.x * 2];
        lp += zv.x + zv.y;
    }
#pragma unroll
    for (int m = 32; m >= 1; m >>= 1) lp += __shfl_xor(lp, m, 64);
    __shared__ float bl[4];
    if (lane == 0) bl[threadIdx.x >> 6] = lp;
    __syncthreads();
    if (threadIdx.x == 0)
        atomicAdd(lossp, (bl[0] + bl[1] + bl[2] + bl[3]) * LOSS_SCALE);
}

// ---------------------------------------------------------------------------
// C: pure gather z_q = codebook[idx] — reads only idx (outside scratch) + cb;
// float4 stores (4x fewer store instructions than R16's scalar writes).
__global__ __launch_bounds__(256)
void vq_gather_kernel(const float* __restrict__ cb, float* __restrict__ out) {
    const float* idxf = out + IDX_OFF;
    __shared__ float crow[64][257];
    __shared__ int kidx[64];
    int t = threadIdx.x;
    int w = t >> 6, lane = t & 63;
    int n0 = blockIdx.x * 64;                      // grid 512
    int b = n0 >> 10, hw0 = n0 & 1023;
    if (t < 64) kidx[t] = (int)idxf[n0 + t];
    __syncthreads();
    for (int i = 0; i < 16; ++i) {                 // stage 64 code rows (1KB/wave)
        int r = w * 16 + i;
        int k = kidx[r];
        float4 v = *(const float4*)(cb + (size_t)k * DD + lane * 4);
        crow[r][lane * 4 + 0] = v.x; crow[r][lane * 4 + 1] = v.y;
        crow[r][lane * 4 + 2] = v.z; crow[r][lane * 4 + 3] = v.w;
    }
    __syncthreads();
    // write z_q with float4 stores: thread = (c4 = t&15 float4-col, zph = t>>4)
    const int c4  = t & 15;
    const int zph = t >> 4;
#pragma unroll 4
    for (int dd = 0; dd < 16; ++dd) {
        int d = dd * 16 + zph;
        float4 v;
        v.x = crow[c4 * 4 + 0][d];
        v.y = crow[c4 * 4 + 1][d];
        v.z = crow[c4 * 4 + 2][d];
        v.w = crow[c4 * 4 + 3][d];
        *(float4*)(out + (size_t)b * (DD * HWD) + (size_t)d * HWD + hw0 + c4 * 4) = v;
    }
}

// ---------------------------------------------------------------------------
extern "C" void kernel_launch(void* const* d_in, const int* in_sizes, int n_in,
                              void* d_out, int out_size, void* d_ws, size_t ws_size,
                              hipStream_t stream) {
    const float* z  = (const float*)d_in[0];
    const float* cb = (const float*)d_in[1];
    float* out = (float*)d_out;
    unsigned char* scratch = (unsigned char*)d_out;   // z_q region, overwritten by gather

    hipMemsetAsync((void*)(out + LOSS_OFF), 0, sizeof(float), stream);

    vq_prep_kernel<<<64, 256, 0, stream>>>(cb, scratch);
    vq_mfma_argmin_kernel<<<512, 256, 0, stream>>>(z, scratch);
    vq_refine_kernel<<<128, 256, 0, stream>>>(z, cb, scratch, out + IDX_OFF, out + LOSS_OFF);
    vq_gather_kernel<<<512, 256, 0, stream>>>(cb, out);
}

// Round 20
// 67.882 us; speedup vs baseline: 1.0942x; 1.0942x over previous
//
#include <hip/hip_runtime.h>
#include <hip/hip_bf16.h>
#include <hip/hip_fp16.h>

#define DD  256
#define HWD 1024
#define NN  32768
#define KK  1024
#define ZQ_SIZE (NN*DD)
#define IDX_OFF ZQ_SIZE
#define LOSS_OFF (ZQ_SIZE + NN)

// scratch layout (bytes) inside the z_q region of d_out (overwritten by gather)
#define CBH_OFF    0                      // fp16 codebook, 512 KB
#define CNORM_OFF  (KK*DD*2)              // 4 KB (biased +512)
#define ZSQ_OFF    (CNORM_OFF + KK*4)     // 512 floats (per-block zsq partials)
#define ROWREC_OFF (ZSQ_OFF + 2048)       // 4 floats/row packed top-3, 512 KB

#define DBIAS 512.0f
#define TH_REFINE 0.5f                     // >= 2*(fp16 err + pack err) + idx-bit slack
#define LOSS_SCALE (0.25f / (float)ZQ_SIZE)

typedef __attribute__((ext_vector_type(8))) _Float16 h16x8;
typedef __attribute__((ext_vector_type(4))) float f32x4;

__device__ __forceinline__ void gload16(const void* g, void* l) {
    __builtin_amdgcn_global_load_lds(
        (const __attribute__((address_space(1))) void*)g,
        (__attribute__((address_space(3))) void*)l, 16, 0, 0);
}
__device__ __forceinline__ unsigned short f16u(float x) {
    _Float16 h = (_Float16)x;
    return *reinterpret_cast<unsigned short*>(&h);
}
// bijective row swizzle: 2-way on both stride-1 reads and stride-4 writes
__device__ __forceinline__ int swz(int row) {
    return (row & 15) ^ ((row >> 2) & 15);
}

// ---------------------------------------------------------------------------
// A: codebook -> fp16 + fp32 row norms (biased by +DBIAS for packing)
__global__ __launch_bounds__(256)
void vq_prep_kernel(const float* __restrict__ cb, unsigned char* __restrict__ scratch) {
    _Float16* cbh = (_Float16*)(scratch + CBH_OFF);
    float* cn = (float*)(scratch + CNORM_OFF);
    int t = threadIdx.x;
    int row = blockIdx.x * 16 + (t >> 4);   // grid 64
    int dq  = t & 15;
    const float* rp = cb + (size_t)row * DD + dq * 16;
    float nrm = 0.f;
    __attribute__((aligned(16))) _Float16 h[16];
#pragma unroll
    for (int i = 0; i < 4; ++i) {
        float4 v = *(const float4*)(rp + i * 4);
        float xs[4] = {v.x, v.y, v.z, v.w};
#pragma unroll
        for (int j = 0; j < 4; ++j) {
            float x = xs[j];
            h[i * 4 + j] = (_Float16)x;
            nrm = fmaf(x, x, nrm);
        }
    }
    *(uint4*)&cbh[(size_t)row * DD + dq * 16]     = *(uint4*)&h[0];
    *(uint4*)&cbh[(size_t)row * DD + dq * 16 + 8] = *(uint4*)&h[8];
#pragma unroll
    for (int m = 1; m < 16; m <<= 1) nrm += __shfl_xor(nrm, m, 64);
    if (dq == 0) cn[row] = nrm + DBIAS;
}

// ---------------------------------------------------------------------------
// B: fp16 MFMA distance-argmin (R16 verbatim — best measured: ~47.5 us)
__global__ __launch_bounds__(256) __attribute__((amdgpu_waves_per_eu(2, 2)))
void vq_mfma_argmin_kernel(const float* __restrict__ z, unsigned char* __restrict__ scratch) {
    const unsigned char* cbh_b = scratch + CBH_OFF;
    const float* cn_g = (const float*)(scratch + CNORM_OFF);
    float* zsqp = (float*)(scratch + ZSQ_OFF);
    float* rowrec = (float*)(scratch + ROWREC_OFF);

    __shared__ __attribute__((aligned(16))) short bufs[4 * 8192];  // 64 KB
    __shared__ float cn_l[KK];                                     // 4 KB (biased)
    __shared__ float zred[4];

    const int t    = threadIdx.x;
    const int w    = t >> 6;
    const int lane = t & 63;
    const int ln15 = lane & 15;
    const int lh   = lane >> 4;
    const int g     = w >> 1;        // row-group 0..1 (32 rows each)
    const int khalf = w & 1;         // 16-code half of each 32-code tile

    const int n0  = blockIdx.x * 64;
    const int b   = n0 >> 10;
    const int hw0 = n0 & 1023;

    const int ksub  = lane >> 5;
    const int chunk = lane & 31;

    const int klr   = khalf * 16 + ln15;     // code row within 32-code tile
    const int rbase = klr * 256;             // shorts
    const int rxor  = swz(klr) << 3;         // swizzle (short units)

    *(float4*)&cn_l[t * 4] = *(const float4*)(cn_g + t * 4);

    // ---- phase 1: coalesced z -> LDS (fp16, transposed, swizzled; short2 writes)
    {
        short* zlds = bufs;
        const int zd = t >> 4;               // 0..15: d-block zd*16..+15
        const int zq = t & 15;               // rows zq*4..+3
        const float* zb = z + (size_t)b * DD * HWD + hw0 + zq * 4;
        float zsq = 0.f;
#pragma unroll
        for (int p = 0; p < 16; p += 2) {
            int d0 = zd * 16 + p;
            float4 va = *(const float4*)(zb + (size_t)(d0 + 0) * HWD);
            float4 vb = *(const float4*)(zb + (size_t)(d0 + 1) * HWD);
            zsq = fmaf(va.x, va.x, zsq); zsq = fmaf(va.y, va.y, zsq);
            zsq = fmaf(va.z, va.z, zsq); zsq = fmaf(va.w, va.w, zsq);
            zsq = fmaf(vb.x, vb.x, zsq); zsq = fmaf(vb.y, vb.y, zsq);
            zsq = fmaf(vb.z, vb.z, zsq); zsq = fmaf(vb.w, vb.w, zsq);
            float xa[4] = {va.x, va.y, va.z, va.w};
            float xb[4] = {vb.x, vb.y, vb.z, vb.w};
#pragma unroll
            for (int i = 0; i < 4; ++i) {
                int row = zq * 4 + i;
                int idx = row * 256 + (d0 ^ (swz(row) << 3));   // even, b32-aligned
                unsigned pk = (unsigned)f16u(xa[i]) | ((unsigned)f16u(xb[i]) << 16);
                *(unsigned*)&zlds[idx] = pk;
            }
        }
#pragma unroll
        for (int m = 1; m < 64; m <<= 1) zsq += __shfl_xor(zsq, m, 64);
        if (lane == 0) zred[w] = zsq;
    }
    __syncthreads();

    // ---- phase 2: A-frags from LDS
    h16x8 ah[2][8];
#pragma unroll
    for (int nf = 0; nf < 2; ++nf) {
#pragma unroll
        for (int ds = 0; ds < 8; ++ds) {
            int row = g * 32 + nf * 16 + ln15;
            int d0  = ds * 32 + lh * 8;
            ah[nf][ds] = *(const h16x8*)&bufs[row * 256 + (d0 ^ (swz(row) << 3))];
        }
    }
    if (t == 0) zsqp[blockIdx.x] = (zred[0] + zred[1]) + (zred[2] + zred[3]);
    __syncthreads();   // all frag reads done before staging overwrites bufs

    auto STAGE = [&](int tt) {
#pragma unroll
        for (int si = 0; si < 4; ++si) {
            int s  = w * 4 + si;
            int kl = s * 2 + ksub;
            const unsigned char* src = cbh_b
                + (size_t)(tt * 32 + kl) * 512 + ((chunk ^ swz(kl)) << 4);
            gload16(src, &bufs[(tt & 3) * 8192 + s * 512]);
        }
    };

    float v1[8], v2[8];
#pragma unroll
    for (int s = 0; s < 8; ++s) { v1[s] = 3e38f; v2[s] = 3e38f; }

    auto COMPUTE = [&](int kt) {
        const short* cbt = &bufs[(kt & 3) * 8192];
        const float cnv = cn_l[kt * 32 + klr];               // biased
        const unsigned kbits = (unsigned)(kt * 32 + klr);
        f32x4 c0 = {0.f,0.f,0.f,0.f}, c1 = c0, c2 = c0, c3 = c0;
#pragma unroll
        for (int ds = 0; ds < 8; ds += 2) {
            const int ib0 = rbase + (((ds + 0) * 32 + lh * 8) ^ rxor);
            const int ib1 = rbase + (((ds + 1) * 32 + lh * 8) ^ rxor);
            h16x8 b0 = *(const h16x8*)&cbt[ib0];
            h16x8 b1 = *(const h16x8*)&cbt[ib1];
            c0 = __builtin_amdgcn_mfma_f32_16x16x32_f16(ah[0][ds + 0], b0, c0, 0, 0, 0);
            c2 = __builtin_amdgcn_mfma_f32_16x16x32_f16(ah[1][ds + 0], b0, c2, 0, 0, 0);
            c1 = __builtin_amdgcn_mfma_f32_16x16x32_f16(ah[0][ds + 1], b1, c1, 0, 0, 0);
            c3 = __builtin_amdgcn_mfma_f32_16x16x32_f16(ah[1][ds + 1], b1, c3, 0, 0, 0);
        }
        f32x4 s0 = c0 + c1, s1 = c2 + c3;
#pragma unroll
        for (int s = 0; s < 8; ++s) {
            float a = (s < 4) ? s0[s] : s1[s - 4];
            float dist = fmaf(-2.f, a, cnv);                 // positive (biased)
            float pd = __uint_as_float((__float_as_uint(dist) & 0xFFFFFC00u) | kbits);
            v2[s] = fminf(fmaxf(pd, v1[s]), v2[s]);          // med3
            v1[s] = fminf(pd, v1[s]);
        }
    };

    STAGE(0); STAGE(1); STAGE(2);

    for (int kt = 0; kt < 29; ++kt) {
        asm volatile("s_waitcnt vmcnt(8)" ::: "memory");
        __builtin_amdgcn_sched_barrier(0);
        __builtin_amdgcn_s_barrier();
        __builtin_amdgcn_sched_barrier(0);
        STAGE(kt + 3);
        COMPUTE(kt);
    }
    asm volatile("s_waitcnt vmcnt(8)" ::: "memory");
    __builtin_amdgcn_sched_barrier(0);
    __builtin_amdgcn_s_barrier();
    __builtin_amdgcn_sched_barrier(0);
    COMPUTE(29);
    asm volatile("s_waitcnt vmcnt(4)" ::: "memory");
    __builtin_amdgcn_sched_barrier(0);
    __builtin_amdgcn_s_barrier();
    __builtin_amdgcn_sched_barrier(0);
    COMPUTE(30);
    asm volatile("s_waitcnt vmcnt(0)" ::: "memory");
    __builtin_amdgcn_sched_barrier(0);
    __builtin_amdgcn_s_barrier();
    __builtin_amdgcn_sched_barrier(0);
    COMPUTE(31);

    // ---- per-row top-3 merge on packed floats (alias bufs; stride-65 pad)
    __syncthreads();
    float* redv = (float*)bufs;              // [64 lists][stride 65]
#pragma unroll
    for (int s = 0; s < 8; ++s) {
        int nf = s >> 2, r = s & 3;
        int rowb = g * 32 + nf * 16 + lh * 4 + r;   // C layout: row = lh*4+reg
        redv[klr * 65 + rowb]        = v1[s];
        redv[(32 + klr) * 65 + rowb] = v2[s];
    }
    __syncthreads();

    const int p = t >> 6, row = t & 63;
    float w1 = 3e38f, w2 = 3e38f, w3 = 3e38f;
#pragma unroll
    for (int q = 0; q < 16; ++q) {
        float v = redv[(p * 16 + q) * 65 + row];
        w3 = fminf(fmaxf(v, w2), w3);
        w2 = fminf(fmaxf(v, w1), w2);
        w1 = fminf(v, w1);
    }
    __syncthreads();
    {   // partials: [4 p][64 rows][3]
        float* pv = (float*)bufs;
        int base = (p * 64 + row) * 3;
        pv[base + 0] = w1; pv[base + 1] = w2; pv[base + 2] = w3;
    }
    __syncthreads();
    if (t < 64) {
        const float* pv = (const float*)bufs;
        float u1 = 3e38f, u2 = 3e38f, u3 = 3e38f;
#pragma unroll
        for (int i = 0; i < 12; ++i) {
            float v = pv[((i / 3) * 64 + t) * 3 + (i % 3)];
            u3 = fminf(fmaxf(v, u2), u3);
            u2 = fminf(fmaxf(v, u1), u2);
            u1 = fminf(v, u1);
        }
        float4 rec; rec.x = u1; rec.y = u2; rec.z = u3; rec.w = 0.f;
        *(float4*)&rowrec[(size_t)(n0 + t) * 4] = rec;
    }
}

// ---------------------------------------------------------------------------
// R: flagged rows (packed gap <= TH) -> exact fp32 recheck of top-3;
// loss = sum chosen dist + zsq partials (block 0). (R16 verbatim — passed.)
__global__ __launch_bounds__(256)
void vq_refine_kernel(const float* __restrict__ z, const float* __restrict__ cb,
                      const unsigned char* __restrict__ scratch, float* __restrict__ idx_out,
                      float* __restrict__ lossp) {
    const float* rowrec = (const float*)(scratch + ROWREC_OFF);
    const float* cn_g = (const float*)(scratch + CNORM_OFF);   // biased
    const float* zsqp = (const float*)(scratch + ZSQ_OFF);
    int n = blockIdx.x * 256 + threadIdx.x;   // grid 128
    int lane = threadIdx.x & 63;

    float4 rr = *(const float4*)&rowrec[(size_t)n * 4];
    unsigned b1 = __float_as_uint(rr.x);
    bool flag = (rr.y - rr.x) <= TH_REFINE;
    float lp = 0.f;
    if (!flag) {
        idx_out[n] = (float)(b1 & 1023u);
        lp = __uint_as_float(b1 & 0xFFFFFC00u) - DBIAS;   // approx dist for loss
    }

    unsigned long long mask = __ballot(flag);
    while (mask) {
        int li = __ffsll(mask) - 1;
        mask &= mask - 1;
        int nn  = __shfl(n, li);
        int kk1 = (int)(__float_as_uint(__shfl(rr.x, li)) & 1023u);
        int kk2 = (int)(__float_as_uint(__shfl(rr.y, li)) & 1023u);
        int kk3 = (int)(__float_as_uint(__shfl(rr.z, li)) & 1023u);
        int bb = nn >> 10, hw = nn & 1023;
        const float* zp  = z  + (size_t)bb * DD * HWD + hw;
        const float* c1p = cb + (size_t)kk1 * DD;
        const float* c2p = cb + (size_t)kk2 * DD;
        const float* c3p = cb + (size_t)kk3 * DD;
        float s1 = 0.f, s2 = 0.f, s3 = 0.f;
#pragma unroll
        for (int j = 0; j < 4; ++j) {
            int d = lane + 64 * j;
            float zv = zp[(size_t)d * HWD];
            s1 = fmaf(zv, c1p[d], s1);
            s2 = fmaf(zv, c2p[d], s2);
            s3 = fmaf(zv, c3p[d], s3);
        }
#pragma unroll
        for (int m = 32; m >= 1; m >>= 1) {
            s1 += __shfl_xor(s1, m, 64);
            s2 += __shfl_xor(s2, m, 64);
            s3 += __shfl_xor(s3, m, 64);
        }
        float e1 = (cn_g[kk1] - DBIAS) - 2.f * s1;
        float e2 = (cn_g[kk2] - DBIAS) - 2.f * s2;
        float e3 = (cn_g[kk3] - DBIAS) - 2.f * s3;
        float dch = e1; int kch = kk1;
        if (e2 < dch || (e2 == dch && kk2 < kch)) { dch = e2; kch = kk2; }
        if (e3 < dch || (e3 == dch && kk3 < kch)) { dch = e3; kch = kk3; }
        if (lane == 0) { idx_out[nn] = (float)kch; lp += dch; }
    }

    // fold zsq partials (block 0; 512 floats, 2/thread)
    if (blockIdx.x == 0) {
        const float2 zv = *(const float2*)&zsqp[threadIdx.x * 2];
        lp += zv.x + zv.y;
    }
#pragma unroll
    for (int m = 32; m >= 1; m >>= 1) lp += __shfl_xor(lp, m, 64);
    __shared__ float bl[4];
    if (lane == 0) bl[threadIdx.x >> 6] = lp;
    __syncthreads();
    if (threadIdx.x == 0)
        atomicAdd(lossp, (bl[0] + bl[1] + bl[2] + bl[3]) * LOSS_SCALE);
}

// ---------------------------------------------------------------------------
// C: pure gather z_q = codebook[idx] (tiled via LDS, coalesced writes)
// (R16 verbatim — the measured-best variant.)
__global__ __launch_bounds__(256)
void vq_gather_kernel(const float* __restrict__ cb, float* __restrict__ out) {
    const float* idxf = out + IDX_OFF;
    __shared__ float crow[64][257];
    __shared__ int kidx[64];
    int t = threadIdx.x;
    int w = t >> 6, lane = t & 63;
    int n0 = blockIdx.x * 64;                      // grid 512
    int b = n0 >> 10, hw0 = n0 & 1023;
    if (t < 64) kidx[t] = (int)idxf[n0 + t];
    __syncthreads();
    for (int i = 0; i < 16; ++i) {                 // stage 64 code rows (1KB/wave)
        int r = w * 16 + i;
        int k = kidx[r];
        float4 v = *(const float4*)(cb + (size_t)k * DD + lane * 4);
        crow[r][lane * 4 + 0] = v.x; crow[r][lane * 4 + 1] = v.y;
        crow[r][lane * 4 + 2] = v.z; crow[r][lane * 4 + 3] = v.w;
    }
    __syncthreads();
    const int zph = t >> 6, hwl = t & 63;
#pragma unroll 4
    for (int dd = 0; dd < 64; ++dd) {
        int d = dd * 4 + zph;
        size_t o = (size_t)b * (DD * HWD) + (size_t)d * HWD + hw0 + hwl;
        out[o] = crow[hwl][d];
    }
}

// ---------------------------------------------------------------------------
extern "C" void kernel_launch(void* const* d_in, const int* in_sizes, int n_in,
                              void* d_out, int out_size, void* d_ws, size_t ws_size,
                              hipStream_t stream) {
    const float* z  = (const float*)d_in[0];
    const float* cb = (const float*)d_in[1];
    float* out = (float*)d_out;
    unsigned char* scratch = (unsigned char*)d_out;   // z_q region, overwritten by gather

    hipMemsetAsync((void*)(out + LOSS_OFF), 0, sizeof(float), stream);

    vq_prep_kernel<<<64, 256, 0, stream>>>(cb, scratch);
    vq_mfma_argmin_kernel<<<512, 256, 0, stream>>>(z, scratch);
    vq_refine_kernel<<<128, 256, 0, stream>>>(z, cb, scratch, out + IDX_OFF, out + LOSS_OFF);
    vq_gather_kernel<<<512, 256, 0, stream>>>(cb, out);
}